// Round 7
// baseline (273.820 us; speedup 1.0000x reference)
//
#include <hip/hip_runtime.h>
#include <math.h>

typedef __attribute__((ext_vector_type(8))) short short8;
typedef __attribute__((ext_vector_type(4))) float f32x4;

#define B_   4
#define N_   1024
#define FTOT 3264
#define FPAD 3328

// workspace offsets (bytes)
#define WS_SS   0
#define WS_ABF  151552
#define WS_PT   8540160

__device__ __forceinline__ unsigned short f2bf(float x) {
  union { float f; unsigned u; } v; v.f = x;
  unsigned r = v.u + 0x7FFFu + ((v.u >> 16) & 1u);
  return (unsigned short)(r >> 16);
}

__device__ __forceinline__ void gload16(const void* gp, void* lp) {
  __builtin_amdgcn_global_load_lds((const __attribute__((address_space(1))) unsigned int*)gp,
                                   (__attribute__((address_space(3))) unsigned int*)lp, 16, 0, 0);
}

__device__ __forceinline__ float wave_sum(float v) {
#pragma unroll
  for (int off = 32; off > 0; off >>= 1) v += __shfl_down(v, off, 64);
  return v;
}

// ---------------- CG coefficient machinery ----------------
__device__ double dfact(int n) { double r = 1.0; for (int i = 2; i <= n; ++i) r *= (double)i; return r; }

__device__ float cg_coeff(int l1, int m1, int l2, int m2, int L, int M) {
  if (m1 + m2 != M) return 0.f;
  int dl = l1 - l2; if (dl < 0) dl = -dl;
  if (L < dl || L > l1 + l2) return 0.f;
  double pre = sqrt((double)(2*L+1) * dfact(L+l1-l2) * dfact(L-l1+l2) * dfact(l1+l2-L) / dfact(l1+l2+L+1));
  pre *= sqrt(dfact(L+M)*dfact(L-M)*dfact(l1-m1)*dfact(l1+m1)*dfact(l2-m2)*dfact(l2+m2));
  double s = 0.0;
  for (int k = 0; k <= l1 + l2 - L; ++k) {
    int d1 = l1+l2-L-k, d2 = l1-m1-k, d3 = l2+m2-k, d4 = L-l2+m1+k, d5 = L-l1-m2+k;
    if (d1 < 0 || d2 < 0 || d3 < 0 || d4 < 0 || d5 < 0) continue;
    double t = (k & 1) ? -1.0 : 1.0;
    t /= dfact(k)*dfact(d1)*dfact(d2)*dfact(d3)*dfact(d4)*dfact(d5);
    s += t;
  }
  return (float)(pre * s);
}

// 15 CG tables in (L, frag) order; dense [i][j][k] layout, offsets below.
__device__ const int t_l1[15]  = {0,1,2, 0,1,1,1,2,2, 0,1,1,2,2,2};
__device__ const int t_l2[15]  = {0,1,2, 1,0,1,2,1,2, 2,1,2,0,1,2};
__device__ const int t_L [15]  = {0,0,0, 1,1,1,1,1,1, 2,2,2,2,2,2};
__device__ const int t_off[16] = {0,1,10, 35,44,53,80,125,170, 245,270,315,390,415,490, 615};

// per-L frag decode tables (frag order = reference's (l1,l2) loop order)
__device__ const int d_l1[3][6]  = {{0,1,2,0,0,0},{0,1,1,1,2,2},{0,1,1,2,2,2}};
__device__ const int d_l2[3][6]  = {{0,1,2,0,0,0},{1,0,1,2,1,2},{2,1,2,0,1,2}};
__device__ const int d_off[3][6] = {{0,1,10,0,0,0},{35,44,53,80,125,170},{245,270,315,390,415,490}};
__device__ const int d_rb[3] = {0, 1, 4};   // row base of degree l in the 9-row (m) stack

// cg_emit: CG products for one (vertex m, 4-channel group), RS = vsh row stride
template <int L, int RS>
__device__ __forceinline__ void cg_emit(const float* vme, const float sxr[9],
                                        const float* cgt,
                                        unsigned short* pout, int cbase) {
  const int nfrag = (L == 0) ? 3 : 6;
  const int nk = 2 * L + 1;
  const int Lbase = (L == 0) ? 0 : (L == 1 ? 192 : 1344);
  const int Cfrag = nfrag * 64;
#pragma unroll
  for (int frag = 0; frag < nfrag; ++frag) {
    const int l1 = d_l1[L][frag], l2 = d_l2[L][frag];
    const int n1 = 2 * l1 + 1, n2 = 2 * l2 + 1;
    const int rb1 = d_rb[l1], rb2 = d_rb[l2];
    const int cgo = d_off[L][frag];
#pragma unroll
    for (int k = 0; k < nk; ++k) {
      float w[5];
#pragma unroll
      for (int i = 0; i < n1; ++i) {
        float a = 0.f;
#pragma unroll
        for (int j = 0; j < n2; ++j)
          a += sxr[rb2 + j] * cgt[cgo + (i * n2 + j) * nk + k];
        w[i] = a;
      }
      f32x4 val = {0.f, 0.f, 0.f, 0.f};
#pragma unroll
      for (int i = 0; i < n1; ++i) {
        f32x4 vv = *(const f32x4*)(vme + (rb1 + i) * RS);
        val += vv * w[i];
      }
      const int fb = Lbase + k * Cfrag + frag * 64 + cbase;
      const int ftile = fb >> 7, fr = fb & 127;
      unsigned short* pp = pout + (size_t)ftile * 131072 + (fr >> 4) * 512 + (fr & 15) * 8;
#pragma unroll
      for (int cc = 0; cc < 4; ++cc)
        pp[cc * 8] = f2bf(val[cc]);
    }
  }
}

// K_front: fused {sx-reduce + CG-product} (blocks 0..511, 8 vertex rows each)
//          + adjacency conversion (blocks 512..2559) + ss zero (block 512).
// sx part streams 8 x 36KB s-rows (round-3 proven phase-slot reduce, next row
// prefetched before the barrier); CG table built in LDS under the first loads;
// cgp emit runs out of LDS after the stream -> its mem+VALU hides under the
// delivery-limited s-stream window. Pt layout byte-identical to before.
__global__ __launch_bounds__(256) void k_front(const float* __restrict__ v0, const float* __restrict__ v1,
                                               const float* __restrict__ v2,
                                               const float* __restrict__ s0p, const float* __restrict__ s1p,
                                               const float* __restrict__ s2p,
                                               const int* __restrict__ conn, unsigned short* __restrict__ Abf,
                                               unsigned short* __restrict__ Pt, float* __restrict__ ss) {
  const int tid = threadIdx.x;

  if (blockIdx.x >= 512) {
    // ---- adjacency part ----
    const int idx  = (blockIdx.x - 512) * 256 + tid;   // 0..524287
    const int lane = idx & 63;
    const int w    = (idx >> 6) & 2047;                // wave within batch
    const int b    = idx >> 17;
    const int nt16 = w >> 5;                           // 16-row n tile (0..63)
    const int ks   = w & 31;
    const int l16  = lane & 15, quad = lane >> 4;
    const int n    = nt16 * 16 + l16;
    const int m8   = ks * 32 + quad * 8;
    const int4* src = (const int4*)(conn + ((size_t)(b * 1024 + n) * 1024 + m8));
    int4 c0 = src[0], c1 = src[1];
    short8 o;
    o[0] = f2bf((float)c0.x); o[1] = f2bf((float)c0.y);
    o[2] = f2bf((float)c0.z); o[3] = f2bf((float)c0.w);
    o[4] = f2bf((float)c1.x); o[5] = f2bf((float)c1.y);
    o[6] = f2bf((float)c1.z); o[7] = f2bf((float)c1.w);
    const int nt = n >> 7, nr = n & 127;
    *(short8*)&Abf[(size_t)(b * 8 + nt) * 131072 + ks * 4096 +
                   ((nr >> 4) * 4 + quad) * 128 + (nr & 15) * 8] = o;
    if (blockIdx.x == 512 && tid < 4) ss[tid] = 0.f;   // zero norms + spin counter
    return;
  }

  // ---- fused sx + cgp part: block = (b, 8-row vertex tile) ----
  __shared__ float cgl[616];
  __shared__ float vsh[8 * 580];    // [m 0..7][r 0..8][c 0..63], stride 580 (pad 4)
  __shared__ float red[9][256];
  __shared__ float sxl[8][12];      // per-row 9 m-component sums

  const int b   = blockIdx.x >> 7;       // 0..3
  const int mt8 = blockIdx.x & 127;      // 0..127
  const int n0g = mt8 * 8;
  const size_t nb = (size_t)b * N_ + n0g;

  f32x4 va, vb[3], vc[5];
#define SX_LOAD(RR) do { \
    const f32x4* p0 = (const f32x4*)(s0p + (nb + (RR)) * 1024); \
    const f32x4* p1 = (const f32x4*)(s1p + (nb + (RR)) * 3072); \
    const f32x4* p2 = (const f32x4*)(s2p + (nb + (RR)) * 5120); \
    va = p0[tid]; \
    _Pragma("unroll") for (int it = 0; it < 3; ++it) vb[it] = p1[tid + 256 * it]; \
    _Pragma("unroll") for (int it = 0; it < 5; ++it) vc[it] = p2[tid + 256 * it]; \
  } while (0)

  SX_LOAD(0);

  // build CG table in LDS while the first row's loads are in flight
  for (int t0 = tid; t0 < 615; t0 += 256) {
    int t = 0;
    while (t < 14 && t0 >= t_off[t+1]) ++t;
    int local = t0 - t_off[t];
    int l1 = t_l1[t], l2 = t_l2[t], L = t_L[t];
    int nk = 2*L+1, n2 = 2*l2+1;
    int k = local % nk; int rest = local / nk;
    int j = rest % n2;  int i = rest / n2;
    cgl[t0] = cg_coeff(l1, i - l1, l2, j - l2, L, k - L);
  }

  const int lane = tid & 63, wv = tid >> 6;
  const int r3 = tid % 3;
  const int q5 = (4 * tid) % 5;

  for (int r = 0; r < 8; ++r) {
    // consume row r (round-3 verified phase-slot math, 256 threads)
    float a = va[0] + va[1] + va[2] + va[3];
    float bb[3] = {0.f, 0.f, 0.f};
#pragma unroll
    for (int it = 0; it < 3; ++it)
#pragma unroll
      for (int e = 0; e < 4; ++e)
        bb[(it + e) % 3] += vb[it][e];
    float cc[5] = {0.f, 0.f, 0.f, 0.f, 0.f};
#pragma unroll
    for (int it = 0; it < 5; ++it)
#pragma unroll
      for (int e = 0; e < 4; ++e)
        cc[(4 * it + e) % 5] += vc[it][e];

    if (r < 7) SX_LOAD(r + 1);   // prefetch next row (regs free after accumulate)

    red[0][tid] = a;
#pragma unroll
    for (int u = 0; u < 3; ++u) red[1 + (r3 + u) % 3][tid] = bb[u];
#pragma unroll
    for (int u = 0; u < 5; ++u) red[4 + (q5 + u) % 5][tid] = cc[u];
    __syncthreads();

    for (int rr = wv; rr < 9; rr += 4) {
      float v = red[rr][lane] + red[rr][lane + 64] + red[rr][lane + 128] + red[rr][lane + 192];
      v = wave_sum(v);
      if (lane == 0) sxl[r][rr] = v;
    }
    __syncthreads();
  }
#undef SX_LOAD

  // v-tile: 8 m x 9 r x 64 c -> LDS
  for (int e = tid; e < 1152; e += 256) {
    const int m = e / 144, rest = e % 144;
    const int rr = rest >> 4, c4 = (rest & 15) * 4;
    const size_t vrow = nb + m;
    f32x4 val;
    if (rr == 0)      val = *(const f32x4*)&v0[vrow * 64 + c4];
    else if (rr < 4)  val = *(const f32x4*)&v1[(vrow * 3 + (rr - 1)) * 64 + c4];
    else              val = *(const f32x4*)&v2[(vrow * 5 + (rr - 4)) * 64 + c4];
    *(f32x4*)&vsh[m * 580 + rr * 64 + c4] = val;
  }
  __syncthreads();

  // emit: thread = (m = tid&7, cq = (tid>>3)&15, half = tid>>7)
  const int m  = tid & 7;
  const int cq = (tid >> 3) & 15;
  const int half = tid >> 7;
  const int mg = n0g + m;                          // global contraction index
  const int ks = mg >> 5;
  const int kq = ((mg & 31) >> 3) * 128 + (mg & 7);
  unsigned short* pout = Pt + (size_t)b * 26 * 131072 + ks * 4096 + kq;
  const int cbase = cq * 4;
  float sxr[9];
#pragma unroll
  for (int rr = 0; rr < 9; ++rr) sxr[rr] = sxl[m][rr];
  const float* vme = &vsh[m * 580 + cbase];

  if (half == 0) {
    cg_emit<0, 64>(vme, sxr, cgl, pout, cbase);
    cg_emit<1, 64>(vme, sxr, cgl, pout, cbase);
  } else {
    cg_emit<2, 64>(vme, sxr, cgl, pout, cbase);
    const int fr = 64 + cbase;                     // pad rows [3264,3328)
    unsigned short* pp = pout + (size_t)25 * 131072 + (fr >> 4) * 512 + (fr & 15) * 8;
#pragma unroll
    for (int c2 = 0; c2 < 4; ++c2)
      pp[c2 * 8] = 0;
  }
}

// K4: mp[b][n][f] = sum_m PtT*AbT, with fused normalization.
// 256x256 tile, BK=64, 512 thr (8 waves 2x4), LDS 128KB (2-stage dbuf),
// vmcnt(8) depth-2 pipeline. Grid 208 blocks, 1 block/CU -> all co-resident:
// device spin-barrier on ssv[3], then in-register scale, single out write.
#define WAIT_VM8 0x0F78   // vmcnt=8, expcnt/lgkmcnt nowait
#define WAIT_VM0 0x0F70   // vmcnt=0
#define NBLK 208

__global__ __launch_bounds__(512, 2) void k_gemm(const unsigned short* __restrict__ PtT,
                                                 const unsigned short* __restrict__ AbT,
                                                 float* __restrict__ out, float* __restrict__ ssv) {
  __shared__ unsigned short As[2][2][8192];   // [buf][h: f-half 128 rows][2 ks-chunks]
  __shared__ unsigned short Bs[2][2][8192];   // [buf][h: n-half 128 rows][2 ks-chunks]
  const int i  = blockIdx.x;          // 0..207
  const int x  = i & 7, j = i >> 3;   // x: XCD bucket, j: 0..25
  const int b   = x >> 1;
  const int ntp = 2 * (x & 1) + (j & 1);   // 0..3  (256-n tile)
  const int ftp = j >> 1;                  // 0..12 (256-f tile)
  const int f0 = ftp * 256, n0 = ntp * 256;
  const int tid  = threadIdx.x;
  const int w    = tid >> 6, lane = tid & 63;
  const int wr   = w >> 2, wc = w & 3;     // wave grid 2(M) x 4(N)
  const int l16  = lane & 15, quad = lane >> 4;

  const unsigned short* gA0 = PtT + (size_t)(b * 26 + 2 * ftp    ) * 131072;
  const unsigned short* gA1 = PtT + (size_t)(b * 26 + 2 * ftp + 1) * 131072;
  const unsigned short* gB0 = AbT + (size_t)(b * 8  + 2 * ntp    ) * 131072;
  const unsigned short* gB1 = AbT + (size_t)(b * 8  + 2 * ntp + 1) * 131072;
  const int so = w * 512 + lane * 8;   // per-thread global short offset within a round

#define ISSUE(T, BUF) do { \
    const size_t o = (size_t)(T) * 8192 + so; \
    gload16(gA0 + o,        &As[BUF][0][w * 512]); \
    gload16(gA0 + o + 4096, &As[BUF][0][4096 + w * 512]); \
    gload16(gA1 + o,        &As[BUF][1][w * 512]); \
    gload16(gA1 + o + 4096, &As[BUF][1][4096 + w * 512]); \
    gload16(gB0 + o,        &Bs[BUF][0][w * 512]); \
    gload16(gB0 + o + 4096, &Bs[BUF][0][4096 + w * 512]); \
    gload16(gB1 + o,        &Bs[BUF][1][w * 512]); \
    gload16(gB1 + o + 4096, &Bs[BUF][1][4096 + w * 512]); \
  } while (0)

  f32x4 acc[8][4] = {};
  const int bh  = wc >> 1;            // B half this wave reads
  const int bl4 = (wc & 1) * 4;       // 16-row group base within that half

#define COMPUTE(BUF) do { \
    _Pragma("unroll") \
    for (int kc = 0; kc < 2; ++kc) { \
      short8 bf[4]; \
      _Pragma("unroll") \
      for (int ni = 0; ni < 4; ++ni) \
        bf[ni] = *(const short8*)&Bs[BUF][bh][kc*4096 + ((bl4 + ni)*4 + quad)*128 + l16*8]; \
      _Pragma("unroll") \
      for (int mh = 0; mh < 2; ++mh) { \
        short8 af[4]; \
        _Pragma("unroll") \
        for (int m = 0; m < 4; ++m) \
          af[m] = *(const short8*)&As[BUF][wr][kc*4096 + ((mh*4 + m)*4 + quad)*128 + l16*8]; \
        _Pragma("unroll") \
        for (int m = 0; m < 4; ++m) \
          _Pragma("unroll") \
          for (int ni = 0; ni < 4; ++ni) \
            acc[mh*4 + m][ni] = __builtin_amdgcn_mfma_f32_16x16x32_bf16(af[m], bf[ni], acc[mh*4 + m][ni], 0, 0, 0); \
      } \
    } \
  } while (0)

  ISSUE(0, 0);
  ISSUE(1, 1);
  for (int t = 0; t < 15; ++t) {
    const int buf = t & 1;
    __builtin_amdgcn_s_waitcnt(WAIT_VM8);   // tile t landed; tile t+1 stays in flight
    __builtin_amdgcn_s_barrier();
    COMPUTE(buf);
    __builtin_amdgcn_s_barrier();           // all waves done reading buf
    if (t < 14) ISSUE(t + 2, buf);
  }
  __builtin_amdgcn_s_waitcnt(WAIT_VM0);     // tail: tile 15
  __builtin_amdgcn_s_barrier();
  COMPUTE(1);

  // ---- epilogue pass 1: per-L sumsq of UNSCALED acc ----
  float ssl0 = 0.f, ssl1 = 0.f, ssl2 = 0.f;
#pragma unroll
  for (int mi = 0; mi < 8; ++mi) {
    const int fbase = f0 + wr*128 + mi*16 + quad*4;   // L boundaries are 16-aligned
    if (fbase >= FTOT) continue;
    float sq = 0.f;
#pragma unroll
    for (int ni = 0; ni < 4; ++ni) {
      f32x4 v = acc[mi][ni];
      sq += v[0]*v[0] + v[1]*v[1] + v[2]*v[2] + v[3]*v[3];
    }
    if (fbase < 192) ssl0 += sq; else if (fbase < 1344) ssl1 += sq; else ssl2 += sq;
  }
  ssl0 = wave_sum(ssl0); ssl1 = wave_sum(ssl1); ssl2 = wave_sum(ssl2);

  __syncthreads();                           // LDS free for reuse
  float* red = (float*)&As[0][0][0];
  if (lane == 0) { red[w*3 + 0] = ssl0; red[w*3 + 1] = ssl1; red[w*3 + 2] = ssl2; }
  __syncthreads();
  if (tid < 3) {
    float s = 0.f;
#pragma unroll
    for (int ww = 0; ww < 8; ++ww) s += red[ww*3 + tid];
    if (s != 0.f) atomicAdd(&ssv[tid], s);
  }
  __syncthreads();

  // ---- device spin barrier (all 208 blocks co-resident: 1 block/CU by LDS) ----
  int* cnt = (int*)(ssv + 3);                // zeroed by k_front each launch
  if (tid == 0) {
    __threadfence();
    atomicAdd(cnt, 1);                       // arrival
    while (atomicAdd(cnt, 0) < NBLK) __builtin_amdgcn_s_sleep(8);
  }
  __syncthreads();

  if (tid < 3) red[tid] = atomicAdd(&ssv[tid], 0.f);
  __syncthreads();
  const float sc0 = 64.f / (1.f * sqrtf(red[0]));
  const float sc1 = 64.f / (3.f * sqrtf(red[1]));
  const float sc2 = 64.f / (5.f * sqrtf(red[2]));

  // ---- epilogue pass 2: scaled store (out written exactly once) ----
#pragma unroll
  for (int mi = 0; mi < 8; ++mi) {
    const int fbase = f0 + wr*128 + mi*16 + quad*4;
    if (fbase >= FTOT) continue;
    const float sc = fbase < 192 ? sc0 : (fbase < 1344 ? sc1 : sc2);
#pragma unroll
    for (int ni = 0; ni < 4; ++ni) {
      const int n = n0 + wc*64 + ni*16 + l16;
      f32x4 v = acc[mi][ni];
      v *= sc;
      *(f32x4*)&out[((size_t)b * N_ + n) * FTOT + fbase] = v;
    }
  }
#undef ISSUE
#undef COMPUTE
}

extern "C" void kernel_launch(void* const* d_in, const int* in_sizes, int n_in,
                              void* d_out, int out_size, void* d_ws, size_t ws_size,
                              hipStream_t stream) {
  const float* v0 = (const float*)d_in[0];
  const float* v1 = (const float*)d_in[1];
  const float* v2 = (const float*)d_in[2];
  const float* s0 = (const float*)d_in[3];
  const float* s1 = (const float*)d_in[4];
  const float* s2 = (const float*)d_in[5];
  const int* conn = (const int*)d_in[6];
  char* ws = (char*)d_ws;
  float* ss            = (float*)(ws + WS_SS);
  unsigned short* Abf  = (unsigned short*)(ws + WS_ABF);
  unsigned short* Pt   = (unsigned short*)(ws + WS_PT);
  float* out = (float*)d_out;

  k_front<<<dim3(2560), dim3(256), 0, stream>>>(v0, v1, v2, s0, s1, s2, conn, Abf, Pt, ss);
  k_gemm <<<dim3(208),  dim3(512), 0, stream>>>(Pt, Abf, out, ss);
}